// Round 4
// baseline (1157.581 us; speedup 1.0000x reference)
//
#include <hip/hip_runtime.h>
#include <hip/hip_cooperative_groups.h>
#include <stdint.h>
namespace cg = cooperative_groups;

typedef __bf16 bf16x8 __attribute__((ext_vector_type(8)));
typedef float f32x4 __attribute__((ext_vector_type(4)));

__device__ __forceinline__ float b2f(unsigned short u){
  unsigned int t = ((unsigned int)u) << 16;
  return __builtin_bit_cast(float, t);
}
__device__ __forceinline__ unsigned short f2b(float f){
  unsigned int x = __builtin_bit_cast(unsigned int, f);
  x = x + 0x7FFFu + ((x >> 16) & 1u);
  return (unsigned short)(x >> 16);
}
// spread 8 bits -> 8 packed bf16 {0.0,1.0} (element j = bit j)
__device__ __forceinline__ void spread8(unsigned int B, unsigned int w[4]){
  unsigned int m = __umul24(B, 0x8001u);
  w[0] = __umul24(m & 0x00010001u, 0x3F80u);
  w[1] = __umul24(m & 0x00040004u, 0x0FE0u);
  w[2] = __umul24(m & 0x00100010u, 0x03F8u);
  w[3] = __umul24(m & 0x00400040u, 0x00FEu);
}
__device__ __forceinline__ float fsig(float x){ return 1.f/(1.f + __expf(-x)); }
__device__ __forceinline__ float ftanh(float x){ return 1.f - 2.f/(__expf(2.f*x) + 1.f); }

// ---- prep: dtype-vote + convert all weights to canonical bf16 + zero deg/seg/cnt ----
__global__ void k_prep(const void* s_msgW, const void* s_msgb, const void* s_wih,
                       const void* s_whh, const void* s_bih, const void* s_bhh,
                       const void* s_poolW, const void* s_poolb,
                       const unsigned short* __restrict__ aemb_u16,
                       unsigned short* __restrict__ cw,
                       int* __restrict__ deg, float* __restrict__ seg,
                       float* __restrict__ cnt, int* __restrict__ flag){
  int b = blockIdx.x, t = threadIdx.x;
  // per-wave dtype vote on aemb even-index u16s (bf16 -> sane exponents)
  unsigned int uu = aemb_u16[2*t];
  int e = (int)((uu >> 7) & 0xFF);
  unsigned long long vote = __ballot(e >= 100 && e <= 127);
  int isb = (__popcll(vote) > 32) ? 1 : 0;
  if (b < 1771){
    int id = b*256 + t;
    if (id < 453248){
      const void* src; int off;
      if      (id < 163840){ src = s_msgW;  off = id; }
      else if (id < 166400){ src = s_msgb;  off = id - 163840; }
      else if (id < 412160){ src = s_wih;   off = id - 166400; }
      else if (id < 442880){ src = s_whh;   off = id - 412160; }
      else if (id < 443840){ src = s_bih;   off = id - 442880; }
      else if (id < 444800){ src = s_bhh;   off = id - 443840; }
      else if (id < 452992){ src = s_poolW; off = id - 444800; }
      else                 { src = s_poolb; off = id - 452992; }
      cw[id] = isb ? ((const unsigned short*)src)[off]
                   : f2b(((const float*)src)[off]);
    }
  } else {
    int id2 = (b - 1771)*256 + t;
    if (id2 < 8192){ deg[id2] = 0; seg[id2] = 0.f; }
    if (id2 < 256) cnt[id2] = 0.f;
    if (b == 1771 && t == 0) flag[0] = isb;
  }
}

// ---- pack adjacency into 16x16x32-A-fragment bit layout + degrees (round-3 verified) ----
__global__ void k_pack(const int* __restrict__ adj, unsigned int* __restrict__ mask3,
                       int* __restrict__ deg){
  int tid = blockIdx.x*256 + threadIdx.x;    // 2,097,152
  int rb  = tid >> 12;
  int rem = tid & 4095;
  int kgg = rem >> 6;
  int L   = rem & 63;
  int lc = L & 15, q = L >> 4;
  int row = rb*16 + lc;
  const int* arow = adj + (size_t)row*8192 + kgg*128 + q*8;
  unsigned int dw = 0; int pc = 0;
  #pragma unroll
  for (int s=0;s<4;s++){
    const int* p = arow + s*32;
    unsigned int b = 0;
    #pragma unroll
    for (int t=0;t<8;t++) b |= (p[t] > 0 ? 1u : 0u) << t;
    dw |= b << (8*s);
    pc += __popc(b);
  }
  mask3[tid] = dw;
  pc += __shfl_xor(pc, 16);
  pc += __shfl_xor(pc, 32);
  if (q == 0) atomicAdd(deg + row, pc);
}

__global__ void k_bond(const int* __restrict__ bft, const void* __restrict__ braw,
                       const int* __restrict__ flag,
                       unsigned short* __restrict__ outB16, float* __restrict__ outB32){
  int id = blockIdx.x*256 + threadIdx.x;
  int e = id >> 5, c = id & 31;
  int idx = bft[e]*32 + c;
  if (flag[0]) outB16[id] = ((const unsigned short*)braw)[idx];
  else         outB32[id] = ((const float*)braw)[idx];
}

// ---- mega: embed + 10 x (neigh | reduce | msg | gi/gh | GRU) + pool ----
__launch_bounds__(256, 2)
__global__ void k_mega(const int* __restrict__ af, const int* __restrict__ bidx,
                       const void* __restrict__ aemb_raw, const int* __restrict__ flag,
                       const unsigned int* __restrict__ mask3,
                       unsigned int* __restrict__ hfrag32,
                       const int* __restrict__ deg,
                       const unsigned short* __restrict__ cw,
                       unsigned short* __restrict__ out16, float* __restrict__ out32,
                       float* __restrict__ seg, float* __restrict__ cnt)
{
  cg::grid_group grid = cg::this_grid();
  __shared__ __align__(16) float          spart[4][16][33];
  __shared__ __align__(16) unsigned short sA[16][72];      // [h(0..32) | neigh(32..64) | pad]
  __shared__ __align__(16) unsigned short smsg[16][264];
  __shared__ float sgi[16][100];
  __shared__ float sgh[16][100];
  __shared__ int   sdeg[16];

  const int t  = threadIdx.x;
  const int b  = blockIdx.x;           // row-tile [0,512)
  const int w  = t >> 6;               // wave
  const int L  = t & 63;
  const int q  = L >> 4, lc = L & 15;
  const int rowbase = b*16;

  // persistent elementwise mapping: thread -> (row r, cols cl, cl+16)
  const int r0 = t >> 4;
  const int cl = t & 15;
  const int r  = rowbase + r0;
  const int isb = flag[0];
  const int dgr = deg[r];
  const float invr = dgr > 0 ? 1.f/(float)dgr : 0.f;
  const int gb = bidx[r];
  if (cl == 0) sdeg[r0] = dgr;

  // ---- embed ----
  float h0, h1;
  {
    int ai = af[r]*32;
    if (isb){ const unsigned short* p = (const unsigned short*)aemb_raw;
              h0 = b2f(p[ai+cl]); h1 = b2f(p[ai+16+cl]); }
    else    { const float* p = (const float*)aemb_raw;
              h0 = p[ai+cl]; h1 = p[ai+16+cl]; }
  }
  // h -> sA h-half + hfrag (B-operand layout), rows paired via shfl_xor(16)
  {
    unsigned int m0 = f2b(h0), m1 = f2b(h1);
    sA[r0][cl] = (unsigned short)m0; sA[r0][16+cl] = (unsigned short)m1;
    unsigned int p0 = (unsigned int)__shfl_xor((int)m0, 16);
    unsigned int p1 = (unsigned int)__shfl_xor((int)m1, 16);
    if ((r & 1) == 0){
      int ks32 = r >> 5;
      int Lf = ((r >> 3) & 3)*16 + cl;
      int pidx = (r & 7) >> 1;
      hfrag32[((ks32*2 + 0)*64 + Lf)*4 + pidx] = m0 | (p0 << 16);
      hfrag32[((ks32*2 + 1)*64 + Lf)*4 + pidx] = m1 | (p1 << 16);
    }
  }
  grid.sync();

  for (int d = 0; d < 10; d++){
    const unsigned short* msgW = cw + (size_t)d*16384;
    const unsigned short* msgb = cw + 163840 + d*256;
    const unsigned short* wih  = cw + 166400 + (size_t)d*24576;
    const unsigned short* whh  = cw + 412160 + d*3072;
    const unsigned short* bih  = cw + 442880 + d*96;
    const unsigned short* bhh  = cw + 443840 + d*96;

    // ---- phase N: wave w = K-chunk kc over this block's 16 rows ----
    {
      f32x4 a0 = {0.f,0.f,0.f,0.f}, a1 = {0.f,0.f,0.f,0.f};
      const unsigned int* mp = mask3 + (size_t)b*4096 + (size_t)w*1024 + L;
      const uint4* bp = (const uint4*)hfrag32 + (size_t)w*8192 + L;
      for (int g=0; g<16; g++){
        unsigned int mw = mp[g*64];
        #pragma unroll
        for (int s=0; s<4; s++){
          int ks = g*4 + s;
          uint4 u0 = bp[(ks*2    )*64];
          uint4 u1 = bp[(ks*2 + 1)*64];
          union { unsigned int u[4]; bf16x8 v; } afr, f0, f1;
          spread8((mw >> (8*s)) & 0xFFu, afr.u);
          f0.u[0]=u0.x; f0.u[1]=u0.y; f0.u[2]=u0.z; f0.u[3]=u0.w;
          f1.u[0]=u1.x; f1.u[1]=u1.y; f1.u[2]=u1.z; f1.u[3]=u1.w;
          a0 = __builtin_amdgcn_mfma_f32_16x16x32_bf16(afr.v, f0.v, a0, 0,0,0);
          a1 = __builtin_amdgcn_mfma_f32_16x16x32_bf16(afr.v, f1.v, a1, 0,0,0);
        }
      }
      #pragma unroll
      for (int rg=0; rg<4; rg++){
        spart[w][q*4+rg][lc]    = a0[rg];
        spart[w][q*4+rg][16+lc] = a1[rg];
      }
    }
    __syncthreads();
    // ---- reduce K-chunks -> sA neigh half ----
    {
      float s0 = spart[0][r0][cl]    + spart[1][r0][cl]    + spart[2][r0][cl]    + spart[3][r0][cl];
      float s1 = spart[0][r0][16+cl] + spart[1][r0][16+cl] + spart[2][r0][16+cl] + spart[3][r0][16+cl];
      sA[r0][32+cl] = f2b(s0*invr);
      sA[r0][48+cl] = f2b(s1*invr);
    }
    __syncthreads();
    // ---- msg GEMM: wave w -> nt = 4w..4w+3 ----
    {
      union { uint4 u; bf16x8 v; } A0, A1;
      A0.u = *(const uint4*)&sA[lc][q*8];
      A1.u = *(const uint4*)&sA[lc][32 + q*8];
      f32x4 am[4];
      #pragma unroll
      for (int i=0;i<4;i++){ am[i][0]=0.f; am[i][1]=0.f; am[i][2]=0.f; am[i][3]=0.f; }
      #pragma unroll
      for (int i=0;i<4;i++){
        int nt = w*4 + i;
        union { uint4 u; bf16x8 v; } B0, B1;
        B0.u = *(const uint4*)(msgW + (size_t)(nt*16 + lc)*64 + q*8);
        B1.u = *(const uint4*)(msgW + (size_t)(nt*16 + lc)*64 + 32 + q*8);
        am[i] = __builtin_amdgcn_mfma_f32_16x16x32_bf16(A0.v, B0.v, am[i], 0,0,0);
        am[i] = __builtin_amdgcn_mfma_f32_16x16x32_bf16(A1.v, B1.v, am[i], 0,0,0);
      }
      #pragma unroll
      for (int i=0;i<4;i++){
        int col = (w*4+i)*16 + lc;
        float bv = b2f(msgb[col]);
        #pragma unroll
        for (int rg=0; rg<4; rg++){
          float v = am[i][rg] + bv;
          if (sdeg[q*4+rg] == 0) v = 0.f;
          smsg[q*4+rg][col] = f2b(v);
        }
      }
    }
    __syncthreads();
    // ---- gi (waves 0-2, 2 nt each) / gh (wave 3, 6 nt) ----
    if (w < 3){
      f32x4 g0 = {0.f,0.f,0.f,0.f}, g1 = {0.f,0.f,0.f,0.f};
      #pragma unroll
      for (int ks=0; ks<8; ks++){
        union { uint4 u; bf16x8 v; } A, B0, B1;
        A.u  = *(const uint4*)&smsg[lc][ks*32 + q*8];
        B0.u = *(const uint4*)(wih + (size_t)((w*2  )*16 + lc)*256 + ks*32 + q*8);
        B1.u = *(const uint4*)(wih + (size_t)((w*2+1)*16 + lc)*256 + ks*32 + q*8);
        g0 = __builtin_amdgcn_mfma_f32_16x16x32_bf16(A.v, B0.v, g0, 0,0,0);
        g1 = __builtin_amdgcn_mfma_f32_16x16x32_bf16(A.v, B1.v, g1, 0,0,0);
      }
      #pragma unroll
      for (int rg=0; rg<4; rg++){
        sgi[q*4+rg][w*32 + lc]      = g0[rg];
        sgi[q*4+rg][w*32 + 16 + lc] = g1[rg];
      }
    } else {
      union { uint4 u; bf16x8 v; } A;
      A.u = *(const uint4*)&sA[lc][q*8];
      f32x4 hh[6];
      #pragma unroll
      for (int nt=0;nt<6;nt++){ hh[nt][0]=0.f; hh[nt][1]=0.f; hh[nt][2]=0.f; hh[nt][3]=0.f; }
      #pragma unroll
      for (int nt=0; nt<6; nt++){
        union { uint4 u; bf16x8 v; } B;
        B.u = *(const uint4*)(whh + (size_t)(nt*16 + lc)*32 + q*8);
        hh[nt] = __builtin_amdgcn_mfma_f32_16x16x32_bf16(A.v, B.v, hh[nt], 0,0,0);
      }
      #pragma unroll
      for (int nt=0; nt<6; nt++)
        #pragma unroll
        for (int rg=0; rg<4; rg++)
          sgh[q*4+rg][nt*16 + lc] = hh[nt][rg];
    }
    __syncthreads();
    // ---- GRU elementwise + write-back ----
    {
      float ir0 = sgi[r0][cl]    + b2f(bih[cl]),    hr0 = sgh[r0][cl]    + b2f(bhh[cl]);
      float iz0 = sgi[r0][32+cl] + b2f(bih[32+cl]), hz0 = sgh[r0][32+cl] + b2f(bhh[32+cl]);
      float in0 = sgi[r0][64+cl] + b2f(bih[64+cl]), hn0 = sgh[r0][64+cl] + b2f(bhh[64+cl]);
      float ir1 = sgi[r0][16+cl] + b2f(bih[16+cl]), hr1 = sgh[r0][16+cl] + b2f(bhh[16+cl]);
      float iz1 = sgi[r0][48+cl] + b2f(bih[48+cl]), hz1 = sgh[r0][48+cl] + b2f(bhh[48+cl]);
      float in1 = sgi[r0][80+cl] + b2f(bih[80+cl]), hn1 = sgh[r0][80+cl] + b2f(bhh[80+cl]);
      float rr0 = fsig(ir0 + hr0), zz0 = fsig(iz0 + hz0);
      float rr1 = fsig(ir1 + hr1), zz1 = fsig(iz1 + hz1);
      float nn0 = ftanh(in0 + rr0*hn0);
      float nn1 = ftanh(in1 + rr1*hn1);
      h0 = (1.f - zz0)*nn0 + zz0*h0;
      h1 = (1.f - zz1)*nn1 + zz1*h1;
      __syncthreads();   // sgi/sgh reads done before anyone's next-layer writes
      unsigned int m0 = f2b(h0), m1 = f2b(h1);
      sA[r0][cl] = (unsigned short)m0; sA[r0][16+cl] = (unsigned short)m1;
      unsigned int p0 = (unsigned int)__shfl_xor((int)m0, 16);
      unsigned int p1 = (unsigned int)__shfl_xor((int)m1, 16);
      if ((r & 1) == 0){
        int ks32 = r >> 5;
        int Lf = ((r >> 3) & 3)*16 + cl;
        int pidx = (r & 7) >> 1;
        hfrag32[((ks32*2 + 0)*64 + Lf)*4 + pidx] = m0 | (p0 << 16);
        hfrag32[((ks32*2 + 1)*64 + Lf)*4 + pidx] = m1 | (p1 << 16);
      }
      if (d == 9){
        if (isb){ out16[r*32 + cl] = (unsigned short)m0; out16[r*32 + 16 + cl] = (unsigned short)m1; }
        else    { out32[r*32 + cl] = h0; out32[r*32 + 16 + cl] = h1; }
        atomicAdd(seg + gb*32 + cl, h0);
        atomicAdd(seg + gb*32 + 16 + cl, h1);
        if (cl == 0) atomicAdd(cnt + gb, 1.f);
      }
    }
    grid.sync();
  }

  // ---- pool (blocks 0..255) ----
  if (b < 256){
    const unsigned short* pw = cw + 444800;
    const unsigned short* pb = cw + 452992;
    float cv = cnt[b];
    float ic = cv > 0.f ? 1.f/cv : 0.f;
    float s = 0.f;
    #pragma unroll
    for (int c=0;c<32;c++) s += seg[b*32+c]*ic*b2f(pw[t*32+c]);
    s += b2f(pb[t]);
    if (isb) out16[1310720 + b*256 + t] = f2b(s);
    else     out32[1310720 + b*256 + t] = s;
  }
}

extern "C" void kernel_launch(void* const* d_in, const int* in_sizes, int n_in,
                              void* d_out, int out_size, void* d_ws, size_t ws_size,
                              hipStream_t stream){
  const int* af   = (const int*)d_in[0];
  const int* bft  = (const int*)d_in[1];
  const int* adj  = (const int*)d_in[2];
  const int* bidx = (const int*)d_in[3];

  char* ws = (char*)d_ws;                                   // ~9.9 MB total
  unsigned int*   mask3 = (unsigned int*)(ws + 0);          // 8 MB
  unsigned int*   hfrag = (unsigned int*)(ws + 8388608);    // 512 KB
  int*            deg   = (int*)(ws + 8912896);             // 32 KB
  float*          seg   = (float*)(ws + 8945664);           // 32 KB
  float*          cnt   = (float*)(ws + 8978432);           // 1 KB
  int*            flag  = (int*)(ws + 8979456);             // 64 B
  unsigned short* cw    = (unsigned short*)(ws + 8979520);  // 906 KB canonical bf16 weights

  unsigned short* o16 = (unsigned short*)d_out;
  float*          o32 = (float*)d_out;

  k_prep<<<1803, 256, 0, stream>>>(d_in[6], d_in[7], d_in[8], d_in[9], d_in[10],
                                   d_in[11], d_in[12], d_in[13],
                                   (const unsigned short*)d_in[4],
                                   cw, deg, seg, cnt, flag);
  k_pack<<<8192, 256, 0, stream>>>(adj, mask3, deg);
  k_bond<<<4096, 256, 0, stream>>>(bft, d_in[5], flag, o16 + 262144, o32 + 262144);

  const void* aemb = d_in[4];
  const unsigned int* mask3c = mask3;
  const int* degc = deg;
  const unsigned short* cwc = cw;
  const int* flagc = flag;
  void* ka[] = { (void*)&af, (void*)&bidx, (void*)&aemb, (void*)&flagc,
                 (void*)&mask3c, (void*)&hfrag, (void*)&degc, (void*)&cwc,
                 (void*)&o16, (void*)&o32, (void*)&seg, (void*)&cnt };
  hipLaunchCooperativeKernel((void*)k_mega, dim3(512), dim3(256), ka, 0, stream);
}

// Round 5
// 532.713 us; speedup vs baseline: 2.1730x; 2.1730x over previous
//
#include <hip/hip_runtime.h>
#include <stdint.h>

typedef __bf16 bf16x8 __attribute__((ext_vector_type(8)));
typedef float f32x4 __attribute__((ext_vector_type(4)));

__device__ __forceinline__ float b2f(unsigned short u){
  unsigned int t = ((unsigned int)u) << 16;
  return __builtin_bit_cast(float, t);
}
__device__ __forceinline__ unsigned short f2b(float f){
  unsigned int x = __builtin_bit_cast(unsigned int, f);
  x = x + 0x7FFFu + ((x >> 16) & 1u);
  return (unsigned short)(x >> 16);
}
// spread 8 bits -> 8 packed bf16 {0.0,1.0} (element j = bit j)
__device__ __forceinline__ void spread8(unsigned int B, unsigned int w[4]){
  unsigned int m = __umul24(B, 0x8001u);
  w[0] = __umul24(m & 0x00010001u, 0x3F80u);
  w[1] = __umul24(m & 0x00040004u, 0x0FE0u);
  w[2] = __umul24(m & 0x00100010u, 0x03F8u);
  w[3] = __umul24(m & 0x00400040u, 0x00FEu);
}
__device__ __forceinline__ float fsig(float x){ return 1.f/(1.f + __expf(-x)); }
__device__ __forceinline__ float ftanh(float x){ return 1.f - 2.f/(__expf(2.f*x) + 1.f); }

// ---- prep: dtype-vote + convert all weights to canonical bf16 + zero deg/seg/cnt ----
__global__ void k_prep(const void* s_msgW, const void* s_msgb, const void* s_wih,
                       const void* s_whh, const void* s_bih, const void* s_bhh,
                       const void* s_poolW, const void* s_poolb,
                       const unsigned short* __restrict__ aemb_u16,
                       unsigned short* __restrict__ cw,
                       int* __restrict__ deg, float* __restrict__ seg,
                       float* __restrict__ cnt, int* __restrict__ flag){
  int b = blockIdx.x, t = threadIdx.x;
  unsigned int uu = aemb_u16[2*t];
  int e = (int)((uu >> 7) & 0xFF);
  unsigned long long vote = __ballot(e >= 100 && e <= 127);
  int isb = (__popcll(vote) > 32) ? 1 : 0;
  if (b < 1771){
    int id = b*256 + t;
    if (id < 453248){
      const void* src; int off;
      if      (id < 163840){ src = s_msgW;  off = id; }
      else if (id < 166400){ src = s_msgb;  off = id - 163840; }
      else if (id < 412160){ src = s_wih;   off = id - 166400; }
      else if (id < 442880){ src = s_whh;   off = id - 412160; }
      else if (id < 443840){ src = s_bih;   off = id - 442880; }
      else if (id < 444800){ src = s_bhh;   off = id - 443840; }
      else if (id < 452992){ src = s_poolW; off = id - 444800; }
      else                 { src = s_poolb; off = id - 452992; }
      cw[id] = isb ? ((const unsigned short*)src)[off]
                   : f2b(((const float*)src)[off]);
    }
  } else {
    int id2 = (b - 1771)*256 + t;
    if (id2 < 8192){ deg[id2] = 0; seg[id2] = 0.f; }
    if (id2 < 256) cnt[id2] = 0.f;
    if (b == 1771 && t == 0) flag[0] = isb;
  }
}

// ---- pack adjacency into 16x16x32-A-fragment bit layout + degrees (r3-verified) ----
__global__ void k_pack(const int* __restrict__ adj, unsigned int* __restrict__ mask3,
                       int* __restrict__ deg){
  int tid = blockIdx.x*256 + threadIdx.x;    // 2,097,152
  int rb  = tid >> 12;
  int rem = tid & 4095;
  int kgg = rem >> 6;
  int L   = rem & 63;
  int lc = L & 15, q = L >> 4;
  int row = rb*16 + lc;
  const int* arow = adj + (size_t)row*8192 + kgg*128 + q*8;
  unsigned int dw = 0; int pc = 0;
  #pragma unroll
  for (int s=0;s<4;s++){
    const int* p = arow + s*32;
    unsigned int b = 0;
    #pragma unroll
    for (int t=0;t<8;t++) b |= (p[t] > 0 ? 1u : 0u) << t;
    dw |= b << (8*s);
    pc += __popc(b);
  }
  mask3[tid] = dw;
  pc += __shfl_xor(pc, 16);
  pc += __shfl_xor(pc, 32);
  if (q == 0) atomicAdd(deg + row, pc);
}

__global__ void k_bond(const int* __restrict__ bft, const void* __restrict__ braw,
                       const int* __restrict__ flag,
                       unsigned short* __restrict__ outB16, float* __restrict__ outB32){
  int id = blockIdx.x*256 + threadIdx.x;
  int e = id >> 5, c = id & 31;
  int idx = bft[e]*32 + c;
  if (flag[0]) outB16[id] = ((const unsigned short*)braw)[idx];
  else         outB32[id] = ((const float*)braw)[idx];
}

// ---- embed: hf32 + hfrag0 (B-operand layout), r3-verified algebra ----
__global__ void k_embed(const int* __restrict__ af, const void* __restrict__ araw,
                        const int* __restrict__ flag,
                        float* __restrict__ hf32, uint4* __restrict__ hfrag){
  __shared__ __align__(16) float sh[512];
  int t = threadIdx.x;
  int r = t >> 5, c = t & 31;
  int row = blockIdx.x*16 + r;
  int idx = af[row]*32 + c;
  float f;
  if (flag[0]) f = b2f(((const unsigned short*)araw)[idx]);
  else         f = ((const float*)araw)[idx];
  hf32[row*32 + c] = f;
  sh[r*32 + c] = f;
  __syncthreads();
  if (t < 64){
    int nt = t >> 5, Lq = t & 31;
    int ks32 = blockIdx.x >> 1, half = blockIdx.x & 1;
    int col = nt*16 + (Lq & 15);
    int rbase = (Lq >> 4)*8;
    unsigned int w[4];
    #pragma unroll
    for (int p=0;p<4;p++){
      unsigned int lo = f2b(sh[(rbase + 2*p    )*32 + col]);
      unsigned int hi = f2b(sh[(rbase + 2*p + 1)*32 + col]);
      w[p] = lo | (hi << 16);
    }
    hfrag[(ks32*2 + nt)*64 + half*32 + Lq] = make_uint4(w[0],w[1],w[2],w[3]);
  }
}

// ---- one full layer per kernel: neigh (8-way K-split) -> reduce -> msg -> gi/gh -> GRU ----
__launch_bounds__(512)
__global__ void k_layer(const unsigned int* __restrict__ mask3,
                        const uint4* __restrict__ hfragIn,
                        unsigned int* __restrict__ hfragOut,
                        float* __restrict__ hf32,
                        const int* __restrict__ deg,
                        const unsigned short* __restrict__ msgW,
                        const unsigned short* __restrict__ msgb,
                        const unsigned short* __restrict__ wih,
                        const unsigned short* __restrict__ whh,
                        const unsigned short* __restrict__ bih,
                        const unsigned short* __restrict__ bhh,
                        const int* __restrict__ bidx,
                        float* __restrict__ seg, float* __restrict__ cnt,
                        unsigned short* __restrict__ out16, float* __restrict__ out32,
                        const int* __restrict__ flag, int last)
{
  __shared__ __align__(16) char uni[33792];                 // spart[8][32][33] f32 | sgi[32][100]+sgh[32][100]
  __shared__ __align__(16) unsigned short sA[32][72];       // [h(0..32)|neigh(32..64)|pad]
  __shared__ __align__(16) unsigned short smsg[32][264];
  __shared__ int sdeg[32];

  const int t = threadIdx.x;
  const int b = blockIdx.x;            // 32-row tile [0,256)
  const int w = t >> 6, L = t & 63;
  const int q = L >> 4, lc = L & 15;
  const int rowbase = b*32;

  // elementwise mapping: thread -> (row r, cols cl and cl+16)
  const int r0 = t >> 4;               // [0,32)
  const int cl = t & 15;
  const int r  = rowbase + r0;
  const int isb = flag[0];
  const int dgr = deg[r];
  const float invr = dgr > 0 ? 1.f/(float)dgr : 0.f;
  float h0 = hf32[r*32 + cl];
  float h1 = hf32[r*32 + 16 + cl];
  sA[r0][cl]    = f2b(h0);
  sA[r0][16+cl] = f2b(h1);
  if (cl == 0) sdeg[r0] = dgr;

  // ---- neigh: wave w = K-chunk of 1024 cols; 2 row-tiles (rt) of 16 ----
  {
    f32x4 a00={0,0,0,0}, a01={0,0,0,0}, a10={0,0,0,0}, a11={0,0,0,0};
    const unsigned int* mp = mask3 + (size_t)b*8192 + w*512 + L;     // rt stride 4096
    const uint4* bp = hfragIn + (size_t)w*4096 + L;
    for (int g=0; g<8; g++){
      unsigned int mw0 = mp[g*64];
      unsigned int mw1 = mp[4096 + g*64];
      #pragma unroll
      for (int s=0; s<4; s++){
        int ks = g*4 + s;
        uint4 u0 = bp[ks*128];
        uint4 u1 = bp[ks*128 + 64];
        union { unsigned int u[4]; bf16x8 v; } A0, A1, B0, B1;
        spread8((mw0 >> (8*s)) & 0xFFu, A0.u);
        spread8((mw1 >> (8*s)) & 0xFFu, A1.u);
        B0.u[0]=u0.x; B0.u[1]=u0.y; B0.u[2]=u0.z; B0.u[3]=u0.w;
        B1.u[0]=u1.x; B1.u[1]=u1.y; B1.u[2]=u1.z; B1.u[3]=u1.w;
        a00 = __builtin_amdgcn_mfma_f32_16x16x32_bf16(A0.v, B0.v, a00, 0,0,0);
        a01 = __builtin_amdgcn_mfma_f32_16x16x32_bf16(A0.v, B1.v, a01, 0,0,0);
        a10 = __builtin_amdgcn_mfma_f32_16x16x32_bf16(A1.v, B0.v, a10, 0,0,0);
        a11 = __builtin_amdgcn_mfma_f32_16x16x32_bf16(A1.v, B1.v, a11, 0,0,0);
      }
    }
    float* sp = (float*)uni + w*1056;                      // [32][33]
    #pragma unroll
    for (int rg=0; rg<4; rg++){
      int rw = q*4 + rg;
      sp[rw*33 + lc]         = a00[rg];
      sp[rw*33 + 16 + lc]    = a01[rg];
      sp[(16+rw)*33 + lc]    = a10[rg];
      sp[(16+rw)*33 + 16+lc] = a11[rg];
    }
  }
  __syncthreads();
  // ---- reduce 8 K-chunks -> sA neigh half ----
  {
    const float* spf = (const float*)uni;
    float s0 = 0.f, s1 = 0.f;
    #pragma unroll
    for (int ww=0; ww<8; ww++){
      s0 += spf[ww*1056 + r0*33 + cl];
      s1 += spf[ww*1056 + r0*33 + 16 + cl];
    }
    sA[r0][32+cl] = f2b(s0*invr);
    sA[r0][48+cl] = f2b(s1*invr);
  }
  __syncthreads();
  // ---- msg GEMM: wave w -> rt=w&1, nt = (w>>1)*4 .. +3 ----
  {
    int rt = w & 1, ntb = (w >> 1)*4;
    union { uint4 u; bf16x8 v; } A0, A1;
    A0.u = *(const uint4*)&sA[rt*16 + lc][q*8];
    A1.u = *(const uint4*)&sA[rt*16 + lc][32 + q*8];
    #pragma unroll
    for (int i=0; i<4; i++){
      int nt = ntb + i;
      union { uint4 u; bf16x8 v; } B0, B1;
      B0.u = *(const uint4*)(msgW + (size_t)(nt*16 + lc)*64 + q*8);
      B1.u = *(const uint4*)(msgW + (size_t)(nt*16 + lc)*64 + 32 + q*8);
      f32x4 am = {0,0,0,0};
      am = __builtin_amdgcn_mfma_f32_16x16x32_bf16(A0.v, B0.v, am, 0,0,0);
      am = __builtin_amdgcn_mfma_f32_16x16x32_bf16(A1.v, B1.v, am, 0,0,0);
      float bv = b2f(msgb[nt*16 + lc]);
      #pragma unroll
      for (int rg=0; rg<4; rg++){
        int rw = rt*16 + q*4 + rg;
        float v = am[rg] + bv;
        if (sdeg[rw] == 0) v = 0.f;
        smsg[rw][nt*16 + lc] = f2b(v);
      }
    }
  }
  __syncthreads();
  // ---- gi (waves 0-5: nt=w, both rt) / gh (waves 6-7: rt=w-6, nt 0..5) ----
  {
    float* sgi = (float*)uni;                               // [32][100]
    float* sgh = (float*)(uni + 12800);                     // [32][100]
    if (w < 6){
      int nt = w;
      f32x4 g0 = {0,0,0,0}, g1 = {0,0,0,0};
      #pragma unroll
      for (int ks=0; ks<8; ks++){
        union { uint4 u; bf16x8 v; } A0, A1, B;
        B.u  = *(const uint4*)(wih + (size_t)(nt*16 + lc)*256 + ks*32 + q*8);
        A0.u = *(const uint4*)&smsg[lc][ks*32 + q*8];
        A1.u = *(const uint4*)&smsg[16 + lc][ks*32 + q*8];
        g0 = __builtin_amdgcn_mfma_f32_16x16x32_bf16(A0.v, B.v, g0, 0,0,0);
        g1 = __builtin_amdgcn_mfma_f32_16x16x32_bf16(A1.v, B.v, g1, 0,0,0);
      }
      #pragma unroll
      for (int rg=0; rg<4; rg++){
        sgi[(q*4+rg)*100      + nt*16 + lc] = g0[rg];
        sgi[(16+q*4+rg)*100   + nt*16 + lc] = g1[rg];
      }
    } else {
      int rt = w - 6;
      union { uint4 u; bf16x8 v; } A;
      A.u = *(const uint4*)&sA[rt*16 + lc][q*8];
      #pragma unroll
      for (int nt=0; nt<6; nt++){
        union { uint4 u; bf16x8 v; } B;
        B.u = *(const uint4*)(whh + (size_t)(nt*16 + lc)*32 + q*8);
        f32x4 hh = {0,0,0,0};
        hh = __builtin_amdgcn_mfma_f32_16x16x32_bf16(A.v, B.v, hh, 0,0,0);
        #pragma unroll
        for (int rg=0; rg<4; rg++)
          sgh[(rt*16 + q*4+rg)*100 + nt*16 + lc] = hh[rg];
      }
    }
  }
  __syncthreads();
  // ---- GRU elementwise + hfragOut write (r4-verified pairing) ----
  {
    const float* sgi = (const float*)uni;
    const float* sgh = (const float*)(uni + 12800);
    float ir0 = sgi[r0*100 + cl]    + b2f(bih[cl]),    hr0 = sgh[r0*100 + cl]    + b2f(bhh[cl]);
    float iz0 = sgi[r0*100 + 32+cl] + b2f(bih[32+cl]), hz0 = sgh[r0*100 + 32+cl] + b2f(bhh[32+cl]);
    float in0 = sgi[r0*100 + 64+cl] + b2f(bih[64+cl]), hn0 = sgh[r0*100 + 64+cl] + b2f(bhh[64+cl]);
    float ir1 = sgi[r0*100 + 16+cl] + b2f(bih[16+cl]), hr1 = sgh[r0*100 + 16+cl] + b2f(bhh[16+cl]);
    float iz1 = sgi[r0*100 + 48+cl] + b2f(bih[48+cl]), hz1 = sgh[r0*100 + 48+cl] + b2f(bhh[48+cl]);
    float in1 = sgi[r0*100 + 80+cl] + b2f(bih[80+cl]), hn1 = sgh[r0*100 + 80+cl] + b2f(bhh[80+cl]);
    float rr0 = fsig(ir0 + hr0), zz0 = fsig(iz0 + hz0);
    float rr1 = fsig(ir1 + hr1), zz1 = fsig(iz1 + hz1);
    float nn0 = ftanh(in0 + rr0*hn0);
    float nn1 = ftanh(in1 + rr1*hn1);
    h0 = (1.f - zz0)*nn0 + zz0*h0;
    h1 = (1.f - zz1)*nn1 + zz1*h1;
    hf32[r*32 + cl]      = h0;
    hf32[r*32 + 16 + cl] = h1;
    unsigned int m0 = f2b(h0), m1 = f2b(h1);
    unsigned int p0 = (unsigned int)__shfl_xor((int)m0, 16);
    unsigned int p1 = (unsigned int)__shfl_xor((int)m1, 16);
    if ((r & 1) == 0){
      int ks32 = r >> 5;
      int Lf = ((r >> 3) & 3)*16 + cl;
      int pidx = (r & 7) >> 1;
      hfragOut[((ks32*2 + 0)*64 + Lf)*4 + pidx] = m0 | (p0 << 16);
      hfragOut[((ks32*2 + 1)*64 + Lf)*4 + pidx] = m1 | (p1 << 16);
    }
    if (last){
      if (isb){ out16[r*32 + cl] = (unsigned short)m0; out16[r*32 + 16 + cl] = (unsigned short)m1; }
      else    { out32[r*32 + cl] = h0; out32[r*32 + 16 + cl] = h1; }
      int gb = bidx[r];
      atomicAdd(seg + gb*32 + cl, h0);
      atomicAdd(seg + gb*32 + 16 + cl, h1);
      if (cl == 0) atomicAdd(cnt + gb, 1.f);
    }
  }
}

__global__ void k_pool(const float* __restrict__ seg, const float* __restrict__ cnt,
                       const unsigned short* __restrict__ pw, const unsigned short* __restrict__ pb,
                       const int* __restrict__ flag,
                       unsigned short* __restrict__ outG16, float* __restrict__ outG32){
  int g = blockIdx.x, o = threadIdx.x;
  float cv = cnt[g];
  float ic = cv > 0.f ? 1.f/cv : 0.f;
  float s = 0.f;
  #pragma unroll
  for (int c=0;c<32;c++) s += seg[g*32+c]*ic*b2f(pw[o*32+c]);
  s += b2f(pb[o]);
  if (flag[0]) outG16[g*256 + o] = f2b(s);
  else         outG32[g*256 + o] = s;
}

extern "C" void kernel_launch(void* const* d_in, const int* in_sizes, int n_in,
                              void* d_out, int out_size, void* d_ws, size_t ws_size,
                              hipStream_t stream){
  const int* af   = (const int*)d_in[0];
  const int* bft  = (const int*)d_in[1];
  const int* adj  = (const int*)d_in[2];
  const int* bidx = (const int*)d_in[3];

  char* ws = (char*)d_ws;                                    // ~11.5 MB total
  unsigned int*   mask3  = (unsigned int*)(ws + 0);          // 8 MB
  unsigned int*   hfrag0 = (unsigned int*)(ws + 8388608);    // 512 KB
  unsigned int*   hfrag1 = (unsigned int*)(ws + 8912896);    // 512 KB
  float*          hf32   = (float*)(ws + 9437184);           // 1 MB
  int*            deg    = (int*)(ws + 10485760);            // 32 KB
  float*          seg    = (float*)(ws + 10518528);          // 32 KB
  float*          cnt    = (float*)(ws + 10551296);          // 1 KB
  int*            flag   = (int*)(ws + 10552320);            // 64 B
  unsigned short* cw     = (unsigned short*)(ws + 10552384); // 906 KB canonical bf16 weights

  unsigned short* o16 = (unsigned short*)d_out;
  float*          o32 = (float*)d_out;

  k_prep<<<1803, 256, 0, stream>>>(d_in[6], d_in[7], d_in[8], d_in[9], d_in[10],
                                   d_in[11], d_in[12], d_in[13],
                                   (const unsigned short*)d_in[4],
                                   cw, deg, seg, cnt, flag);
  k_pack<<<8192, 256, 0, stream>>>(adj, mask3, deg);
  k_bond<<<4096, 256, 0, stream>>>(bft, d_in[5], flag, o16 + 262144, o32 + 262144);
  k_embed<<<512, 512, 0, stream>>>(af, d_in[4], flag, hf32, (uint4*)hfrag0);

  for (int d = 0; d < 10; d++){
    const uint4*  hin  = (const uint4*)((d & 1) ? hfrag1 : hfrag0);
    unsigned int* hout = (d & 1) ? hfrag0 : hfrag1;
    k_layer<<<256, 512, 0, stream>>>(mask3, hin, hout, hf32, deg,
                                     cw + (size_t)d*16384,        cw + 163840 + d*256,
                                     cw + 166400 + (size_t)d*24576, cw + 412160 + d*3072,
                                     cw + 442880 + d*96,          cw + 443840 + d*96,
                                     bidx, seg, cnt, o16, o32, flag, (d == 9) ? 1 : 0);
  }
  k_pool<<<256, 256, 0, stream>>>(seg, cnt, cw + 444800, cw + 452992, flag,
                                  o16 + 1310720, o32 + 1310720);
}